// Round 5
// baseline (182.687 us; speedup 1.0000x reference)
//
#include <hip/hip_runtime.h>

#define BATCH 32
#define HDIM 224
#define WDIM 224
#define CDIM 3
#define KTOT (HDIM * WDIM * CDIM)   // 150528
#define HID 64
#define KC 128                       // k-chunk per block
#define NBLK1 (KTOT / KC)            // 1176
#define PIX (HDIM * WDIM)            // 50176
#define BLK3 49                      // 256 thr * 4 px = 1024 px per block

// ---------------- Kernel 1: part[blk] = flat[:,kslice] @ w1[kslice,:] --------
// 4 waves partition the 32 batches (8 each) -> block partials are disjoint,
// no cross-wave reduce. Lane owns 4 contiguous hids ((lane&15)*4+c) and 2
// batches (bq=lane>>4). One ds_read_b128 of x feeds 16 FMAs. The k-subblock
// order is rotated by bq so the 4 broadcast addresses land on disjoint banks.
__global__ __launch_bounds__(256, 4) void k1_gemm(const float* __restrict__ flat,
                                                  const float* __restrict__ w1,
                                                  float* __restrict__ part) {
    __shared__ float smem[BATCH * KC];           // 16 KB
    const int tid  = threadIdx.x;
    const int lane = tid & 63;
    const int wave = tid >> 6;
    const int h4   = lane & 15;                  // hid group: hids h4*4..h4*4+3
    const int bq   = lane >> 4;                  // 0..3
    const int b0   = wave * 8 + bq * 2;          // lane's 2 batches
    const int k0   = blockIdx.x * KC;

    // --- Stage flat[32][k0..k0+KC) into LDS, coalesced float4 ---
#pragma unroll
    for (int t = 0; t < 4; ++t) {
        const int idx = tid + t * 256;           // 0..1023 float4 slots
        const int b   = idx >> 5;                // 32 slots per row (KC/4)
        const int kq  = idx & 31;
        *(float4*)(&smem[b * KC + kq * 4]) =
            *(const float4*)(flat + (size_t)b * KTOT + k0 + kq * 4);
    }
    __syncthreads();

    float4 acc[2];
    acc[0] = make_float4(0.f, 0.f, 0.f, 0.f);
    acc[1] = make_float4(0.f, 0.f, 0.f, 0.f);

    for (int p = 0; p < 8; ++p) {                // 8 passes x 16 k
        const int kp = p * 16;

        // prefetch w: wr[s*4+j] = w1[k0+kp+((s+bq)&3)*4+j][h4*4 .. +4]
        float4 wr[16];
#pragma unroll
        for (int s = 0; s < 4; ++s) {
            const int sp = ((s + bq) & 3) * 4;
#pragma unroll
            for (int j = 0; j < 4; ++j)
                wr[s * 4 + j] = *(const float4*)(
                    w1 + (size_t)(k0 + kp + sp + j) * HID + h4 * 4);
        }

#pragma unroll
        for (int s = 0; s < 4; ++s) {
            const int sp = ((s + bq) & 3) * 4;
#pragma unroll
            for (int b = 0; b < 2; ++b) {
                const float4 x = *(const float4*)(&smem[(b0 + b) * KC + kp + sp]);
                const float xs[4] = {x.x, x.y, x.z, x.w};
                float* A = (float*)&acc[b];
#pragma unroll
                for (int j = 0; j < 4; ++j) {
                    const float* wf = (const float*)&wr[s * 4 + j];
#pragma unroll
                    for (int c = 0; c < 4; ++c)
                        A[c] = fmaf(xs[j], wf[c], A[c]);
                }
            }
        }
    }

    // --- Stream disjoint partials (no reduce, no atomics) ---
    float* po = part + (size_t)blockIdx.x * 2048;
#pragma unroll
    for (int b = 0; b < 2; ++b)
        *(float4*)(po + (b0 + b) * HID + h4 * 4) = acc[b];
}

// ---------------- Kernel 1b: hacc = sum over 1176 blocks of part -------------
__global__ __launch_bounds__(256) void k1_reduce(const float* __restrict__ part,
                                                 float* __restrict__ hacc) {
    __shared__ float red[256];
    const int tid    = threadIdx.x;
    const int o      = tid & 31;
    const int g      = tid >> 5;                 // 0..7
    const int o_base = blockIdx.x * 32;

    float s = 0.0f;
    for (int blk = g; blk < NBLK1; blk += 8)
        s += part[(size_t)blk * 2048 + o_base + o];
    red[tid] = s;
    __syncthreads();
    if (g == 0) {
        float t = 0.0f;
#pragma unroll
        for (int gg = 0; gg < 8; ++gg)
            t += red[gg * 32 + o];
        hacc[o_base + o] = t;
    }
}

// -------- Kernel 3: head recompute + affine grid + bilinear sampling --------
__global__ __launch_bounds__(256) void k3_sample(const float* __restrict__ img,
                                                 const float* __restrict__ hacc,
                                                 const float* __restrict__ b1,
                                                 const float* __restrict__ w2,
                                                 const float* __restrict__ b2,
                                                 float* __restrict__ out) {
    const int b     = blockIdx.x / BLK3;
    const int strip = blockIdx.x - b * BLK3;
    const int tid   = threadIdx.x;

    __shared__ float sh[HID];
    __shared__ float sth[6];
    if (tid < HID)
        sh[tid] = tanhf(hacc[b * HID + tid] + b1[tid]);
    __syncthreads();
    if (tid < 6) {
        float s = b2[tid];
#pragma unroll
        for (int t = 0; t < HID; ++t)
            s = fmaf(sh[t], w2[t * 6 + tid], s);
        sth[tid] = tanhf(s);
    }
    __syncthreads();

    const float t0 = sth[0], t1 = sth[1], t2 = sth[2];
    const float t3 = sth[3], t4 = sth[4], t5 = sth[5];

    const float* base = img + (size_t)b * KTOT;
    const int pix0 = strip * 1024 + tid * 4;

    float res[12];
#pragma unroll
    for (int p = 0; p < 4; ++p) {
        const int pix = pix0 + p;
        const int i = pix / WDIM;
        const int j = pix - i * WDIM;

        const float xt = (2.0f * (float)j - (float)(WDIM - 1)) / (float)(WDIM - 1);
        const float yt = (2.0f * (float)i - (float)(HDIM - 1)) / (float)(HDIM - 1);

        const float xs = t0 * xt + t1 * yt + t2;
        const float ys = t3 * xt + t4 * yt + t5;

        const float x = 0.5f * (xs + 1.0f) * (float)(WDIM - 1);
        const float y = 0.5f * (ys + 1.0f) * (float)(HDIM - 1);

        const int x0 = (int)floorf(x);
        const int y0 = (int)floorf(y);

        const int x0c = min(max(x0, 0), WDIM - 1);
        const int x1c = min(max(x0 + 1, 0), WDIM - 1);
        const int y0c = min(max(y0, 0), HDIM - 1);
        const int y1c = min(max(y0 + 1, 0), HDIM - 1);

        // Reference computes weights from the CLIPPED corner coordinates.
        const float x0f = (float)x0c, x1f = (float)x1c;
        const float y0f = (float)y0c, y1f = (float)y1c;

        const float wa = (x1f - x) * (y1f - y);
        const float wb = (x1f - x) * (y - y0f);
        const float wc = (x - x0f) * (y1f - y);
        const float wd = (x - x0f) * (y - y0f);

        const float* pa = base + (size_t)(y0c * WDIM + x0c) * 3;
        const float* pb = base + (size_t)(y1c * WDIM + x0c) * 3;
        const float* pc = base + (size_t)(y0c * WDIM + x1c) * 3;
        const float* pd = base + (size_t)(y1c * WDIM + x1c) * 3;

#pragma unroll
        for (int c = 0; c < 3; ++c)
            res[p * 3 + c] = wa * pa[c] + wb * pb[c] + wc * pc[c] + wd * pd[c];
    }

    float4* po = (float4*)(out + (size_t)b * KTOT + (size_t)pix0 * 3);
    po[0] = make_float4(res[0], res[1], res[2],  res[3]);
    po[1] = make_float4(res[4], res[5], res[6],  res[7]);
    po[2] = make_float4(res[8], res[9], res[10], res[11]);
}

extern "C" void kernel_launch(void* const* d_in, const int* in_sizes, int n_in,
                              void* d_out, int out_size, void* d_ws, size_t ws_size,
                              hipStream_t stream) {
    const float* inputs = (const float*)d_in[0];
    const float* w1     = (const float*)d_in[1];
    const float* b1     = (const float*)d_in[2];
    const float* w2     = (const float*)d_in[3];
    const float* b2     = (const float*)d_in[4];
    float* out = (float*)d_out;

    float* part = (float*)d_ws;                       // 1176 * 2048 floats
    float* hacc = part + (size_t)NBLK1 * 2048;        // 32*64 floats

    k1_gemm<<<NBLK1, 256, 0, stream>>>(inputs, w1, part);
    k1_reduce<<<HID * BATCH / 32, 256, 0, stream>>>(part, hacc);
    k3_sample<<<BATCH * BLK3, 256, 0, stream>>>(inputs, hacc, b1, w2, b2, out);
}

// Round 6
// 165.658 us; speedup vs baseline: 1.1028x; 1.1028x over previous
//
#include <hip/hip_runtime.h>

#define BATCH 32
#define HDIM 224
#define WDIM 224
#define CDIM 3
#define KTOT (HDIM * WDIM * CDIM)   // 150528
#define HID 64
#define KC 128                       // k-chunk per block
#define NBLK1 (KTOT / KC)            // 1176
#define PIX (HDIM * WDIM)            // 50176
#define BLK3 49                      // 256 thr * 4 px = 1024 px per block

// ---------------- Kernel 1: hacc += flat[:,kslice] @ w1[kslice,:] ------------
// Inverted staging: w1 chunk (shared by all waves) lives in LDS; flat is read
// with wave-uniform SCALAR loads (s_load_dwordx4 -> SGPRs, off the VMEM path).
// Lane = hid (all 64 distinct), wave owns 8 batches -> acc[8]. Per k: one
// conflict-free ds_read_b32 (64 lanes over 32 banks = 2-way, free) feeding
// 8 scalar-operand FMAs. Waves own disjoint batches -> no cross-wave reduce.
__global__ __launch_bounds__(256, 5) void k1_gemm(const float* __restrict__ flat,
                                                  const float* __restrict__ w1,
                                                  float* __restrict__ hacc) {
    __shared__ float sw[KC * HID];               // 32 KB, k-major [k][h]
    const int tid  = threadIdx.x;
    const int lane = tid & 63;                   // hid
    const int b0   = __builtin_amdgcn_readfirstlane((tid >> 6) * 8);
    const int k0   = blockIdx.x * KC;

    // --- Stage w1[k0..k0+KC)[:] into LDS: contiguous 32 KB, coalesced ---
    const float4* wsrc = (const float4*)(w1 + (size_t)k0 * HID);
#pragma unroll
    for (int t = 0; t < 8; ++t) {
        const int idx = tid + t * 256;           // float4 slot 0..2047
        *(float4*)(sw + idx * 4) = wsrc[idx];
    }
    __syncthreads();

    float acc[8];
#pragma unroll
    for (int j = 0; j < 8; ++j) acc[j] = 0.0f;

#pragma unroll 4
    for (int kk = 0; kk < KC; kk += 4) {
        // wave-uniform addresses -> scalar loads into SGPRs
        float4 xs[8];
#pragma unroll
        for (int j = 0; j < 8; ++j)
            xs[j] = *(const float4*)(flat + (size_t)(b0 + j) * KTOT + k0 + kk);
#pragma unroll
        for (int i = 0; i < 4; ++i) {
            const float wv = sw[(kk + i) * HID + lane];
#pragma unroll
            for (int j = 0; j < 8; ++j)
                acc[j] = fmaf(((const float*)&xs[j])[i], wv, acc[j]);
        }
    }

    // --- Disjoint batches per wave: direct coalesced atomics, no reduce ---
#pragma unroll
    for (int j = 0; j < 8; ++j)
        atomicAdd(hacc + (b0 + j) * HID + lane, acc[j]);
}

// -------- Kernel 3: head recompute + affine grid + bilinear sampling --------
__global__ __launch_bounds__(256) void k3_sample(const float* __restrict__ img,
                                                 const float* __restrict__ hacc,
                                                 const float* __restrict__ b1,
                                                 const float* __restrict__ w2,
                                                 const float* __restrict__ b2,
                                                 float* __restrict__ out) {
    const int b     = blockIdx.x / BLK3;
    const int strip = blockIdx.x - b * BLK3;
    const int tid   = threadIdx.x;

    __shared__ float sh[HID];
    __shared__ float sth[6];
    if (tid < HID)
        sh[tid] = tanhf(hacc[b * HID + tid] + b1[tid]);
    __syncthreads();
    if (tid < 6) {
        float s = b2[tid];
#pragma unroll
        for (int t = 0; t < HID; ++t)
            s = fmaf(sh[t], w2[t * 6 + tid], s);
        sth[tid] = tanhf(s);
    }
    __syncthreads();

    const float t0 = sth[0], t1 = sth[1], t2 = sth[2];
    const float t3 = sth[3], t4 = sth[4], t5 = sth[5];

    const float* base = img + (size_t)b * KTOT;
    const int pix0 = strip * 1024 + tid * 4;

    float res[12];
#pragma unroll
    for (int p = 0; p < 4; ++p) {
        const int pix = pix0 + p;
        const int i = pix / WDIM;
        const int j = pix - i * WDIM;

        const float xt = (2.0f * (float)j - (float)(WDIM - 1)) / (float)(WDIM - 1);
        const float yt = (2.0f * (float)i - (float)(HDIM - 1)) / (float)(HDIM - 1);

        const float xs = t0 * xt + t1 * yt + t2;
        const float ys = t3 * xt + t4 * yt + t5;

        const float x = 0.5f * (xs + 1.0f) * (float)(WDIM - 1);
        const float y = 0.5f * (ys + 1.0f) * (float)(HDIM - 1);

        const int x0 = (int)floorf(x);
        const int y0 = (int)floorf(y);

        const int x0c = min(max(x0, 0), WDIM - 1);
        const int x1c = min(max(x0 + 1, 0), WDIM - 1);
        const int y0c = min(max(y0, 0), HDIM - 1);
        const int y1c = min(max(y0 + 1, 0), HDIM - 1);

        // Reference computes weights from the CLIPPED corner coordinates.
        const float x0f = (float)x0c, x1f = (float)x1c;
        const float y0f = (float)y0c, y1f = (float)y1c;

        const float wa = (x1f - x) * (y1f - y);
        const float wb = (x1f - x) * (y - y0f);
        const float wc = (x - x0f) * (y1f - y);
        const float wd = (x - x0f) * (y - y0f);

        const float* pa = base + (size_t)(y0c * WDIM + x0c) * 3;
        const float* pb = base + (size_t)(y1c * WDIM + x0c) * 3;
        const float* pc = base + (size_t)(y0c * WDIM + x1c) * 3;
        const float* pd = base + (size_t)(y1c * WDIM + x1c) * 3;

#pragma unroll
        for (int c = 0; c < 3; ++c)
            res[p * 3 + c] = wa * pa[c] + wb * pb[c] + wc * pc[c] + wd * pd[c];
    }

    float4* po = (float4*)(out + (size_t)b * KTOT + (size_t)pix0 * 3);
    po[0] = make_float4(res[0], res[1], res[2],  res[3]);
    po[1] = make_float4(res[4], res[5], res[6],  res[7]);
    po[2] = make_float4(res[8], res[9], res[10], res[11]);
}

extern "C" void kernel_launch(void* const* d_in, const int* in_sizes, int n_in,
                              void* d_out, int out_size, void* d_ws, size_t ws_size,
                              hipStream_t stream) {
    const float* inputs = (const float*)d_in[0];
    const float* w1     = (const float*)d_in[1];
    const float* b1     = (const float*)d_in[2];
    const float* w2     = (const float*)d_in[3];
    const float* b2     = (const float*)d_in[4];
    float* out = (float*)d_out;

    float* hacc = (float*)d_ws;                  // 32*64 floats = 8 KB only

    hipMemsetAsync(hacc, 0, BATCH * HID * sizeof(float), stream);
    k1_gemm<<<NBLK1, 256, 0, stream>>>(inputs, w1, hacc);
    k3_sample<<<BATCH * BLK3, 256, 0, stream>>>(inputs, hacc, b1, w2, b2, out);
}